// Round 1
// baseline (1224.637 us; speedup 1.0000x reference)
//
#include <hip/hip_runtime.h>
#include <hip/hip_bf16.h>
#include <math.h>

#define NN 50000
#define NE 800000
#define ET (NE + NN)
#define NG 512
#define NEG 0.2f

// ---------------- GEMM: h = x @ W  (M=NN, N=256, K=128/256), 64x64 tile ----
template<int K>
__global__ __launch_bounds__(256) void gemm_kernel(const float* __restrict__ x,
                                                   const float* __restrict__ W,
                                                   float* __restrict__ h) {
    __shared__ float As[16][68];   // [kk][row], padded for banks, 16B-aligned rows
    __shared__ float Bs[16][64];   // [kk][col]
    const int t = threadIdx.x;
    const int tx = t & 15, ty = t >> 4;
    const int m0 = (blockIdx.x >> 2) * 64;
    const int n0 = (blockIdx.x & 3) * 64;
    float c[4][4] = {};
    const int lr = t >> 2;          // 0..63: A row to load
    const int lk = (t & 3) * 4;     // k quad
    const int bkr = t >> 4;         // 0..15: B row
    const int bkc = (t & 15) * 4;   // B col quad
    for (int k0 = 0; k0 < K; k0 += 16) {
        int ar = m0 + lr; if (ar >= NN) ar = NN - 1;
        float4 av = *(const float4*)&x[(long)ar * K + k0 + lk];
        float4 bv = *(const float4*)&W[(long)(k0 + bkr) * 256 + n0 + bkc];
        __syncthreads();
        As[lk + 0][lr] = av.x; As[lk + 1][lr] = av.y;
        As[lk + 2][lr] = av.z; As[lk + 3][lr] = av.w;
        *(float4*)&Bs[bkr][bkc] = bv;
        __syncthreads();
        #pragma unroll
        for (int kk = 0; kk < 16; ++kk) {
            float4 a4 = *(const float4*)&As[kk][ty * 4];
            float4 b4 = *(const float4*)&Bs[kk][tx * 4];
            float a[4] = {a4.x, a4.y, a4.z, a4.w};
            float b[4] = {b4.x, b4.y, b4.z, b4.w};
            #pragma unroll
            for (int i = 0; i < 4; ++i)
                #pragma unroll
                for (int j = 0; j < 4; ++j)
                    c[i][j] = fmaf(a[i], b[j], c[i][j]);
        }
    }
    #pragma unroll
    for (int i = 0; i < 4; ++i) {
        int r = m0 + ty * 4 + i;
        if (r < NN) {
            float4 v = {c[i][0], c[i][1], c[i][2], c[i][3]};
            *(float4*)&h[(long)r * 256 + n0 + tx * 4] = v;
        }
    }
}

// ---------------- per-node attention coefficients --------------------------
__global__ __launch_bounds__(256) void alpha_kernel(const float* __restrict__ h,
        const float* __restrict__ a_src, const float* __restrict__ a_dst,
        float* __restrict__ as_, float* __restrict__ ad_) {
    int n = blockIdx.x * 4 + (threadIdx.x >> 6);
    int lane = threadIdx.x & 63;
    if (n >= NN) return;
    const float* hr = h + (long)n * 256;
    #pragma unroll
    for (int hd = 0; hd < 4; ++hd) {
        float v = hr[hd * 64 + lane];
        float ps = v * a_src[hd * 64 + lane];
        float pd = v * a_dst[hd * 64 + lane];
        #pragma unroll
        for (int off = 32; off; off >>= 1) {
            ps += __shfl_xor(ps, off, 64);
            pd += __shfl_xor(pd, off, 64);
        }
        if (lane == 0) { as_[n * 4 + hd] = ps; ad_[n * 4 + hd] = pd; }
    }
}

// ---------------- CSR-by-dst construction ----------------------------------
__global__ void init_counts(int* counts) {
    int i = blockIdx.x * 256 + threadIdx.x;
    if (i < NN) counts[i] = 1;   // self loop
}
__global__ void count_kernel(const int* __restrict__ dst, int* counts) {
    int e = blockIdx.x * 256 + threadIdx.x;
    if (e < NE) atomicAdd(&counts[dst[e]], 1);
}
__global__ __launch_bounds__(1024) void scan_kernel(const int* __restrict__ counts,
                                                    int* row_ptr, int* cursor) {
    __shared__ int sm[1024];
    const int i = threadIdx.x;
    const int CH = (NN + 1023) / 1024;   // 49
    int base = i * CH;
    int s = 0;
    for (int j = 0; j < CH; ++j) { int idx = base + j; if (idx < NN) s += counts[idx]; }
    sm[i] = s; __syncthreads();
    for (int off = 1; off < 1024; off <<= 1) {
        int v = (i >= off) ? sm[i - off] : 0;
        __syncthreads();
        sm[i] += v;
        __syncthreads();
    }
    int run = sm[i] - s;   // exclusive prefix
    for (int j = 0; j < CH; ++j) {
        int idx = base + j;
        if (idx < NN) { row_ptr[idx] = run; cursor[idx] = run; run += counts[idx]; }
    }
    if (i == 1023) row_ptr[NN] = ET;
}
__global__ void scatter_kernel(const int* __restrict__ src, const int* __restrict__ dst,
                               int* cursor, int* esrc) {
    int e = blockIdx.x * 256 + threadIdx.x;
    if (e < NE) {
        int p = atomicAdd(&cursor[dst[e]], 1);
        esrc[p] = src[e];
    } else if (e < ET) {
        int n = e - NE;
        int p = atomicAdd(&cursor[n], 1);
        esrc[p] = n;
    }
}

// ---------------- segment softmax + aggregation (one wave per dst node) ----
__global__ __launch_bounds__(256) void agg_kernel(const float* __restrict__ h,
        const float* __restrict__ as_, const float* __restrict__ ad_,
        const int* __restrict__ row_ptr, const int* __restrict__ esrc,
        const float* __restrict__ bias, float* __restrict__ out) {
    int n = blockIdx.x * 4 + (threadIdx.x >> 6);
    int lane = threadIdx.x & 63;
    if (n >= NN) return;
    int s0 = row_ptr[n], s1 = row_ptr[n + 1];
    float4 adn = *(const float4*)&ad_[n * 4];
    float m0 = -1e30f, m1 = -1e30f, m2 = -1e30f, m3 = -1e30f;
    for (int i = s0; i < s1; ++i) {
        int s = esrc[i];
        float4 a = *(const float4*)&as_[s * 4];
        float t;
        t = a.x + adn.x; t = t > 0.f ? t : NEG * t; m0 = fmaxf(m0, t);
        t = a.y + adn.y; t = t > 0.f ? t : NEG * t; m1 = fmaxf(m1, t);
        t = a.z + adn.z; t = t > 0.f ? t : NEG * t; m2 = fmaxf(m2, t);
        t = a.w + adn.w; t = t > 0.f ? t : NEG * t; m3 = fmaxf(m3, t);
    }
    float l0 = 0.f, l1 = 0.f, l2 = 0.f, l3 = 0.f;
    float acc0 = 0.f, acc1 = 0.f, acc2 = 0.f, acc3 = 0.f;
    for (int i = s0; i < s1; ++i) {
        int s = esrc[i];
        float4 a = *(const float4*)&as_[s * 4];
        const float* hr = h + (long)s * 256;
        float t, w;
        t = a.x + adn.x; t = t > 0.f ? t : NEG * t; w = __expf(t - m0); l0 += w;
        acc0 = fmaf(w, hr[lane], acc0);
        t = a.y + adn.y; t = t > 0.f ? t : NEG * t; w = __expf(t - m1); l1 += w;
        acc1 = fmaf(w, hr[64 + lane], acc1);
        t = a.z + adn.z; t = t > 0.f ? t : NEG * t; w = __expf(t - m2); l2 += w;
        acc2 = fmaf(w, hr[128 + lane], acc2);
        t = a.w + adn.w; t = t > 0.f ? t : NEG * t; w = __expf(t - m3); l3 += w;
        acc3 = fmaf(w, hr[192 + lane], acc3);
    }
    float* orow = out + (long)n * 256;
    orow[lane]       = acc0 / l0 + bias[lane];
    orow[64 + lane]  = acc1 / l1 + bias[64 + lane];
    orow[128 + lane] = acc2 / l2 + bias[128 + lane];
    orow[192 + lane] = acc3 / l3 + bias[192 + lane];
}

// ---------------- pooling + FC ---------------------------------------------
__global__ void out_init(const float* __restrict__ fc_b, float* out) {
    int i = blockIdx.x * 256 + threadIdx.x;
    if (i < NG) out[i] = fc_b[0];
}
__global__ __launch_bounds__(256) void pool_kernel(const float* __restrict__ h,
        const int* __restrict__ batch, const float* __restrict__ fcW,
        float* __restrict__ out) {
    int n = blockIdx.x * 4 + (threadIdx.x >> 6);
    int lane = threadIdx.x & 63;
    if (n >= NN) return;
    const float* hr = h + (long)n * 256;
    float s = hr[lane] * fcW[lane] + hr[64 + lane] * fcW[64 + lane]
            + hr[128 + lane] * fcW[128 + lane] + hr[192 + lane] * fcW[192 + lane];
    #pragma unroll
    for (int off = 32; off; off >>= 1) s += __shfl_xor(s, off, 64);
    if (lane == 0) atomicAdd(&out[batch[n]], s);
}

extern "C" void kernel_launch(void* const* d_in, const int* in_sizes, int n_in,
                              void* d_out, int out_size, void* d_ws, size_t ws_size,
                              hipStream_t stream) {
    const float* x      = (const float*)d_in[0];
    const int*   ei     = (const int*)d_in[1];     // [2, NE] flattened
    const int*   batch  = (const int*)d_in[2];
    const float* W1     = (const float*)d_in[3];
    const float* as1    = (const float*)d_in[4];
    const float* ad1    = (const float*)d_in[5];
    const float* b1     = (const float*)d_in[6];
    const float* W2     = (const float*)d_in[7];
    const float* as2    = (const float*)d_in[8];
    const float* ad2    = (const float*)d_in[9];
    const float* b2     = (const float*)d_in[10];
    const float* W3     = (const float*)d_in[11];
    const float* as3    = (const float*)d_in[12];
    const float* ad3    = (const float*)d_in[13];
    const float* b3     = (const float*)d_in[14];
    const float* fcW    = (const float*)d_in[15];
    const float* fcb    = (const float*)d_in[16];
    const int* esrc_in = ei;
    const int* edst_in = ei + NE;

    char* ws = (char*)d_ws;
    size_t off = 0;
    float* bufA  = (float*)(ws + off); off += (size_t)NN * 256 * 4;
    float* bufB  = (float*)(ws + off); off += (size_t)NN * 256 * 4;
    float* aS    = (float*)(ws + off); off += (size_t)NN * 4 * 4;
    float* aD    = (float*)(ws + off); off += (size_t)NN * 4 * 4;
    int* counts  = (int*)(ws + off);   off += (size_t)NN * 4;
    int* cursor  = (int*)(ws + off);   off += (size_t)NN * 4;
    int* row_ptr = (int*)(ws + off);   off += (size_t)(NN + 1) * 4 + 12;
    int* esrc    = (int*)(ws + off);   off += (size_t)ET * 4;
    float* out   = (float*)d_out;

    // CSR by dst (same every call; rebuilt deterministically)
    init_counts<<<(NN + 255) / 256, 256, 0, stream>>>(counts);
    count_kernel<<<(NE + 255) / 256, 256, 0, stream>>>(edst_in, counts);
    scan_kernel<<<1, 1024, 0, stream>>>(counts, row_ptr, cursor);
    scatter_kernel<<<(ET + 255) / 256, 256, 0, stream>>>(esrc_in, edst_in, cursor, esrc);

    const int GEMM_GRID = ((NN + 63) / 64) * 4;   // 782 * 4
    const int NODE_GRID = (NN + 3) / 4;           // 12500

    // layer 1
    gemm_kernel<128><<<GEMM_GRID, 256, 0, stream>>>(x, W1, bufA);
    alpha_kernel<<<NODE_GRID, 256, 0, stream>>>(bufA, as1, ad1, aS, aD);
    agg_kernel<<<NODE_GRID, 256, 0, stream>>>(bufA, aS, aD, row_ptr, esrc, b1, bufB);
    // layer 2
    gemm_kernel<256><<<GEMM_GRID, 256, 0, stream>>>(bufB, W2, bufA);
    alpha_kernel<<<NODE_GRID, 256, 0, stream>>>(bufA, as2, ad2, aS, aD);
    agg_kernel<<<NODE_GRID, 256, 0, stream>>>(bufA, aS, aD, row_ptr, esrc, b2, bufB);
    // layer 3
    gemm_kernel<256><<<GEMM_GRID, 256, 0, stream>>>(bufB, W3, bufA);
    alpha_kernel<<<NODE_GRID, 256, 0, stream>>>(bufA, as3, ad3, aS, aD);
    agg_kernel<<<NODE_GRID, 256, 0, stream>>>(bufA, aS, aD, row_ptr, esrc, b3, bufB);

    // pooling + FC
    out_init<<<(NG + 255) / 256, 256, 0, stream>>>(fcb, out);
    pool_kernel<<<NODE_GRID, 256, 0, stream>>>(bufB, batch, fcW, out);
}

// Round 2
// 986.638 us; speedup vs baseline: 1.2412x; 1.2412x over previous
//
#include <hip/hip_runtime.h>
#include <hip/hip_bf16.h>
#include <math.h>

#define NN 50000
#define NE 800000
#define ET (NE + NN)
#define NG 512
#define NEG 0.2f

__device__ inline unsigned f2o(float f) {
    unsigned b = __float_as_uint(f);
    return (b & 0x80000000u) ? ~b : (b | 0x80000000u);
}
__device__ inline float o2f(unsigned u) {
    return (u & 0x80000000u) ? __uint_as_float(u ^ 0x80000000u) : __uint_as_float(~u);
}

// ---- GEMM: h = x @ W  (M=NN, N=256), 64x64 tile, fused alpha epilogue -----
template<int K>
__global__ __launch_bounds__(256) void gemm_kernel(const float* __restrict__ x,
                                                   const float* __restrict__ W,
                                                   float* __restrict__ h,
                                                   const float* __restrict__ a_src,
                                                   const float* __restrict__ a_dst,
                                                   float* __restrict__ as_,
                                                   float* __restrict__ ad_) {
    __shared__ float As[16][68];
    __shared__ float Bs[16][64];
    const int t = threadIdx.x;
    const int tx = t & 15, ty = t >> 4;
    const int m0 = (blockIdx.x >> 2) * 64;
    const int n0 = (blockIdx.x & 3) * 64;
    float c[4][4] = {};
    const int lr = t >> 2;
    const int lk = (t & 3) * 4;
    const int bkr = t >> 4;
    const int bkc = (t & 15) * 4;
    for (int k0 = 0; k0 < K; k0 += 16) {
        int ar = m0 + lr; if (ar >= NN) ar = NN - 1;
        float4 av = *(const float4*)&x[(long)ar * K + k0 + lk];
        float4 bv = *(const float4*)&W[(long)(k0 + bkr) * 256 + n0 + bkc];
        __syncthreads();
        As[lk + 0][lr] = av.x; As[lk + 1][lr] = av.y;
        As[lk + 2][lr] = av.z; As[lk + 3][lr] = av.w;
        *(float4*)&Bs[bkr][bkc] = bv;
        __syncthreads();
        #pragma unroll
        for (int kk = 0; kk < 16; ++kk) {
            float4 a4 = *(const float4*)&As[kk][ty * 4];
            float4 b4 = *(const float4*)&Bs[kk][tx * 4];
            float a[4] = {a4.x, a4.y, a4.z, a4.w};
            float b[4] = {b4.x, b4.y, b4.z, b4.w};
            #pragma unroll
            for (int i = 0; i < 4; ++i)
                #pragma unroll
                for (int j = 0; j < 4; ++j)
                    c[i][j] = fmaf(a[i], b[j], c[i][j]);
        }
    }
    const int head = n0 >> 6;
    float4 asv = *(const float4*)&a_src[head * 64 + tx * 4];
    float4 adv = *(const float4*)&a_dst[head * 64 + tx * 4];
    #pragma unroll
    for (int i = 0; i < 4; ++i) {
        int r = m0 + ty * 4 + i;
        float ps = c[i][0] * asv.x + c[i][1] * asv.y + c[i][2] * asv.z + c[i][3] * asv.w;
        float pd = c[i][0] * adv.x + c[i][1] * adv.y + c[i][2] * adv.z + c[i][3] * adv.w;
        #pragma unroll
        for (int off = 1; off < 16; off <<= 1) {
            ps += __shfl_xor(ps, off, 64);
            pd += __shfl_xor(pd, off, 64);
        }
        if (r < NN) {
            float4 v = {c[i][0], c[i][1], c[i][2], c[i][3]};
            *(float4*)&h[(long)r * 256 + n0 + tx * 4] = v;
            if (tx == 0) { as_[r * 4 + head] = ps; ad_[r * 4 + head] = pd; }
        }
    }
}

// ---- global per-head max of alpha_src --------------------------------------
__global__ void gmax_init(unsigned* gmax) {
    if (threadIdx.x < 4) gmax[threadIdx.x] = 0u;
}
__global__ __launch_bounds__(256) void gmax_reduce(const float* __restrict__ as_,
                                                   unsigned* gmax) {
    float m0 = -1e30f, m1 = -1e30f, m2 = -1e30f, m3 = -1e30f;
    for (int n = blockIdx.x * 256 + threadIdx.x; n < NN; n += gridDim.x * 256) {
        float4 a = *(const float4*)&as_[n * 4];
        m0 = fmaxf(m0, a.x); m1 = fmaxf(m1, a.y);
        m2 = fmaxf(m2, a.z); m3 = fmaxf(m3, a.w);
    }
    #pragma unroll
    for (int off = 32; off; off >>= 1) {
        m0 = fmaxf(m0, __shfl_xor(m0, off, 64));
        m1 = fmaxf(m1, __shfl_xor(m1, off, 64));
        m2 = fmaxf(m2, __shfl_xor(m2, off, 64));
        m3 = fmaxf(m3, __shfl_xor(m3, off, 64));
    }
    __shared__ float sm[4][4];
    int lane = threadIdx.x & 63, w = threadIdx.x >> 6;
    if (lane == 0) { sm[w][0] = m0; sm[w][1] = m1; sm[w][2] = m2; sm[w][3] = m3; }
    __syncthreads();
    if (threadIdx.x == 0) {
        #pragma unroll
        for (int hd = 0; hd < 4; ++hd) {
            float mm = fmaxf(fmaxf(sm[0][hd], sm[1][hd]), fmaxf(sm[2][hd], sm[3][hd]));
            atomicMax(&gmax[hd], f2o(mm));
        }
    }
}

// ---- CSR-by-dst construction ----------------------------------------------
__global__ void init_counts(int* counts) {
    int i = blockIdx.x * 256 + threadIdx.x;
    if (i < NN) counts[i] = 1;
}
__global__ void count_kernel(const int* __restrict__ dst, int* counts) {
    int e = blockIdx.x * 256 + threadIdx.x;
    if (e < NE) atomicAdd(&counts[dst[e]], 1);
}
__global__ __launch_bounds__(1024) void scan_kernel(const int* __restrict__ counts,
                                                    int* row_ptr, int* cursor) {
    __shared__ int sm[1024];
    const int i = threadIdx.x;
    const int CH = (NN + 1023) / 1024;
    int base = i * CH;
    int s = 0;
    for (int j = 0; j < CH; ++j) { int idx = base + j; if (idx < NN) s += counts[idx]; }
    sm[i] = s; __syncthreads();
    for (int off = 1; off < 1024; off <<= 1) {
        int v = (i >= off) ? sm[i - off] : 0;
        __syncthreads();
        sm[i] += v;
        __syncthreads();
    }
    int run = sm[i] - s;
    for (int j = 0; j < CH; ++j) {
        int idx = base + j;
        if (idx < NN) { row_ptr[idx] = run; cursor[idx] = run; run += counts[idx]; }
    }
    if (i == 1023) row_ptr[NN] = ET;
}
__global__ void scatter_kernel(const int* __restrict__ src, const int* __restrict__ dst,
                               int* cursor, int* esrc) {
    int e = blockIdx.x * 256 + threadIdx.x;
    if (e < NE) {
        int p = atomicAdd(&cursor[dst[e]], 1);
        esrc[p] = src[e];
    } else if (e < ET) {
        int n = e - NE;
        int p = atomicAdd(&cursor[n], 1);
        esrc[p] = n;
    }
}

// ---- single-pass segment softmax + aggregation (one wave per dst node) ----
__global__ __launch_bounds__(256) void agg_kernel(const float* __restrict__ h,
        const float* __restrict__ as_, const float* __restrict__ ad_,
        const unsigned* __restrict__ gmax,
        const int* __restrict__ row_ptr, const int* __restrict__ esrc,
        const float* __restrict__ bias, float* __restrict__ out) {
    int n = blockIdx.x * 4 + (threadIdx.x >> 6);
    int lane = threadIdx.x & 63;
    if (n >= NN) return;
    int s0 = row_ptr[n], s1 = row_ptr[n + 1];
    float4 adn = *(const float4*)&ad_[n * 4];
    // upper bound of per-edge logits (leaky monotone): M' = leaky(gmax + ad)
    float g0 = o2f(gmax[0]) + adn.x; g0 = g0 > 0.f ? g0 : NEG * g0;
    float g1 = o2f(gmax[1]) + adn.y; g1 = g1 > 0.f ? g1 : NEG * g1;
    float g2 = o2f(gmax[2]) + adn.z; g2 = g2 > 0.f ? g2 : NEG * g2;
    float g3 = o2f(gmax[3]) + adn.w; g3 = g3 > 0.f ? g3 : NEG * g3;
    float l0 = 0.f, l1 = 0.f, l2 = 0.f, l3 = 0.f;
    float acc0 = 0.f, acc1 = 0.f, acc2 = 0.f, acc3 = 0.f;
    int s = esrc[s0];                        // >=1 edge guaranteed (self-loop)
    for (int i = s0; i < s1; ++i) {
        int snext = esrc[i + 1];             // esrc padded by 1 entry
        float4 a = *(const float4*)&as_[s * 4];
        const float* hr = h + (long)s * 256;
        float h0 = hr[lane], h1 = hr[64 + lane], h2 = hr[128 + lane], h3 = hr[192 + lane];
        float t, w;
        t = a.x + adn.x; t = t > 0.f ? t : NEG * t; w = __expf(t - g0); l0 += w; acc0 = fmaf(w, h0, acc0);
        t = a.y + adn.y; t = t > 0.f ? t : NEG * t; w = __expf(t - g1); l1 += w; acc1 = fmaf(w, h1, acc1);
        t = a.z + adn.z; t = t > 0.f ? t : NEG * t; w = __expf(t - g2); l2 += w; acc2 = fmaf(w, h2, acc2);
        t = a.w + adn.w; t = t > 0.f ? t : NEG * t; w = __expf(t - g3); l3 += w; acc3 = fmaf(w, h3, acc3);
        s = snext;
    }
    float* orow = out + (long)n * 256;
    orow[lane]       = acc0 / l0 + bias[lane];
    orow[64 + lane]  = acc1 / l1 + bias[64 + lane];
    orow[128 + lane] = acc2 / l2 + bias[128 + lane];
    orow[192 + lane] = acc3 / l3 + bias[192 + lane];
}

// ---- pooling + FC ---------------------------------------------------------
__global__ void out_init(const float* __restrict__ fc_b, float* out) {
    int i = blockIdx.x * 256 + threadIdx.x;
    if (i < NG) out[i] = fc_b[0];
}
__global__ __launch_bounds__(256) void pool_kernel(const float* __restrict__ h,
        const int* __restrict__ batch, const float* __restrict__ fcW,
        float* __restrict__ out) {
    int n = blockIdx.x * 4 + (threadIdx.x >> 6);
    int lane = threadIdx.x & 63;
    if (n >= NN) return;
    const float* hr = h + (long)n * 256;
    float s = hr[lane] * fcW[lane] + hr[64 + lane] * fcW[64 + lane]
            + hr[128 + lane] * fcW[128 + lane] + hr[192 + lane] * fcW[192 + lane];
    #pragma unroll
    for (int off = 32; off; off >>= 1) s += __shfl_xor(s, off, 64);
    if (lane == 0) atomicAdd(&out[batch[n]], s);
}

extern "C" void kernel_launch(void* const* d_in, const int* in_sizes, int n_in,
                              void* d_out, int out_size, void* d_ws, size_t ws_size,
                              hipStream_t stream) {
    const float* x      = (const float*)d_in[0];
    const int*   ei     = (const int*)d_in[1];
    const int*   batch  = (const int*)d_in[2];
    const float* W1     = (const float*)d_in[3];
    const float* as1    = (const float*)d_in[4];
    const float* ad1    = (const float*)d_in[5];
    const float* b1     = (const float*)d_in[6];
    const float* W2     = (const float*)d_in[7];
    const float* as2    = (const float*)d_in[8];
    const float* ad2    = (const float*)d_in[9];
    const float* b2     = (const float*)d_in[10];
    const float* W3     = (const float*)d_in[11];
    const float* as3    = (const float*)d_in[12];
    const float* ad3    = (const float*)d_in[13];
    const float* b3     = (const float*)d_in[14];
    const float* fcW    = (const float*)d_in[15];
    const float* fcb    = (const float*)d_in[16];
    const int* esrc_in = ei;
    const int* edst_in = ei + NE;

    char* ws = (char*)d_ws;
    size_t off = 0;
    float* bufA  = (float*)(ws + off); off += (size_t)NN * 256 * 4;
    float* bufB  = (float*)(ws + off); off += (size_t)NN * 256 * 4;
    float* aS    = (float*)(ws + off); off += (size_t)NN * 4 * 4;
    float* aD    = (float*)(ws + off); off += (size_t)NN * 4 * 4;
    int* counts  = (int*)(ws + off);   off += (size_t)NN * 4;
    int* cursor  = (int*)(ws + off);   off += (size_t)NN * 4;
    int* row_ptr = (int*)(ws + off);   off += (size_t)(NN + 1) * 4 + 12;
    unsigned* gmax = (unsigned*)(ws + off); off += 16;
    int* esrc    = (int*)(ws + off);   off += (size_t)(ET + 4) * 4;
    float* out   = (float*)d_out;

    // CSR by dst
    init_counts<<<(NN + 255) / 256, 256, 0, stream>>>(counts);
    count_kernel<<<(NE + 255) / 256, 256, 0, stream>>>(edst_in, counts);
    scan_kernel<<<1, 1024, 0, stream>>>(counts, row_ptr, cursor);
    scatter_kernel<<<(ET + 255) / 256, 256, 0, stream>>>(esrc_in, edst_in, cursor, esrc);

    const int GEMM_GRID = ((NN + 63) / 64) * 4;
    const int NODE_GRID = (NN + 3) / 4;

    // layer 1
    gmax_init<<<1, 64, 0, stream>>>(gmax);
    gemm_kernel<128><<<GEMM_GRID, 256, 0, stream>>>(x, W1, bufA, as1, ad1, aS, aD);
    gmax_reduce<<<128, 256, 0, stream>>>(aS, gmax);
    agg_kernel<<<NODE_GRID, 256, 0, stream>>>(bufA, aS, aD, gmax, row_ptr, esrc, b1, bufB);
    // layer 2
    gmax_init<<<1, 64, 0, stream>>>(gmax);
    gemm_kernel<256><<<GEMM_GRID, 256, 0, stream>>>(bufB, W2, bufA, as2, ad2, aS, aD);
    gmax_reduce<<<128, 256, 0, stream>>>(aS, gmax);
    agg_kernel<<<NODE_GRID, 256, 0, stream>>>(bufA, aS, aD, gmax, row_ptr, esrc, b2, bufB);
    // layer 3
    gmax_init<<<1, 64, 0, stream>>>(gmax);
    gemm_kernel<256><<<GEMM_GRID, 256, 0, stream>>>(bufB, W3, bufA, as3, ad3, aS, aD);
    gmax_reduce<<<128, 256, 0, stream>>>(aS, gmax);
    agg_kernel<<<NODE_GRID, 256, 0, stream>>>(bufA, aS, aD, gmax, row_ptr, esrc, b3, bufB);

    // pooling + FC
    out_init<<<(NG + 255) / 256, 256, 0, stream>>>(fcb, out);
    pool_kernel<<<NODE_GRID, 256, 0, stream>>>(bufB, batch, fcW, out);
}

// Round 3
// 955.349 us; speedup vs baseline: 1.2819x; 1.0328x over previous
//
#include <hip/hip_runtime.h>
#include <hip/hip_bf16.h>
#include <math.h>

#define NN 50000
#define NE 800000
#define ET (NE + NN)
#define NG 512
#define NEG 0.2f

__device__ inline unsigned f2o(float f) {
    unsigned b = __float_as_uint(f);
    return (b & 0x80000000u) ? ~b : (b | 0x80000000u);
}
__device__ inline float o2f(unsigned u) {
    return (u & 0x80000000u) ? __uint_as_float(u ^ 0x80000000u) : __uint_as_float(~u);
}

// ---- GEMM: h = x @ W  (M=NN, N=256), 128x128 tile, 8x8/thread, fused alpha
template<int K>
__global__ __launch_bounds__(256) void gemm_kernel(const float* __restrict__ x,
                                                   const float* __restrict__ W,
                                                   float* __restrict__ h,
                                                   const float* __restrict__ a_src,
                                                   const float* __restrict__ a_dst,
                                                   float* __restrict__ as_,
                                                   float* __restrict__ ad_) {
    __shared__ float As[16][132];
    __shared__ float Bs[16][132];
    const int t = threadIdx.x;
    const int tx = t & 15, ty = t >> 4;
    const int m0 = (blockIdx.x >> 1) * 128;
    const int n0 = (blockIdx.x & 1) * 128;
    float c[8][8] = {};
    const int lr = t >> 1;          // A row 0..127
    const int lk = (t & 1) * 8;     // A k-offset 0/8
    const int br = t >> 4;          // B row 0..15
    const int bc = (t & 15) * 8;    // B col 0..120

    for (int k0 = 0; k0 < K; k0 += 16) {
        int ar = m0 + lr; if (ar >= NN) ar = NN - 1;
        float4 a0 = *(const float4*)&x[(long)ar * K + k0 + lk];
        float4 a1 = *(const float4*)&x[(long)ar * K + k0 + lk + 4];
        float4 b0 = *(const float4*)&W[(long)(k0 + br) * 256 + n0 + bc];
        float4 b1 = *(const float4*)&W[(long)(k0 + br) * 256 + n0 + bc + 4];
        __syncthreads();
        As[lk + 0][lr] = a0.x; As[lk + 1][lr] = a0.y;
        As[lk + 2][lr] = a0.z; As[lk + 3][lr] = a0.w;
        As[lk + 4][lr] = a1.x; As[lk + 5][lr] = a1.y;
        As[lk + 6][lr] = a1.z; As[lk + 7][lr] = a1.w;
        *(float4*)&Bs[br][bc]     = b0;
        *(float4*)&Bs[br][bc + 4] = b1;
        __syncthreads();
        #pragma unroll
        for (int kk = 0; kk < 16; ++kk) {
            float4 A0 = *(const float4*)&As[kk][ty * 4];
            float4 A1 = *(const float4*)&As[kk][64 + ty * 4];
            float4 B0 = *(const float4*)&Bs[kk][tx * 4];
            float4 B1 = *(const float4*)&Bs[kk][64 + tx * 4];
            float av[8] = {A0.x, A0.y, A0.z, A0.w, A1.x, A1.y, A1.z, A1.w};
            float bv[8] = {B0.x, B0.y, B0.z, B0.w, B1.x, B1.y, B1.z, B1.w};
            #pragma unroll
            for (int i = 0; i < 8; ++i)
                #pragma unroll
                for (int j = 0; j < 8; ++j)
                    c[i][j] = fmaf(av[i], bv[j], c[i][j]);
        }
    }

    const int hd0 = n0 >> 6, hd1 = hd0 + 1;
    float4 s0v = *(const float4*)&a_src[hd0 * 64 + tx * 4];
    float4 s1v = *(const float4*)&a_src[hd1 * 64 + tx * 4];
    float4 d0v = *(const float4*)&a_dst[hd0 * 64 + tx * 4];
    float4 d1v = *(const float4*)&a_dst[hd1 * 64 + tx * 4];
    #pragma unroll
    for (int half = 0; half < 2; ++half) {
        #pragma unroll
        for (int i = 0; i < 4; ++i) {
            int ai = half * 4 + i;
            int r = m0 + half * 64 + ty * 4 + i;
            float ps0 = c[ai][0]*s0v.x + c[ai][1]*s0v.y + c[ai][2]*s0v.z + c[ai][3]*s0v.w;
            float pd0 = c[ai][0]*d0v.x + c[ai][1]*d0v.y + c[ai][2]*d0v.z + c[ai][3]*d0v.w;
            float ps1 = c[ai][4]*s1v.x + c[ai][5]*s1v.y + c[ai][6]*s1v.z + c[ai][7]*s1v.w;
            float pd1 = c[ai][4]*d1v.x + c[ai][5]*d1v.y + c[ai][6]*d1v.z + c[ai][7]*d1v.w;
            #pragma unroll
            for (int off = 1; off < 16; off <<= 1) {
                ps0 += __shfl_xor(ps0, off, 64);
                pd0 += __shfl_xor(pd0, off, 64);
                ps1 += __shfl_xor(ps1, off, 64);
                pd1 += __shfl_xor(pd1, off, 64);
            }
            if (r < NN) {
                float4 v0 = {c[ai][0], c[ai][1], c[ai][2], c[ai][3]};
                float4 v1 = {c[ai][4], c[ai][5], c[ai][6], c[ai][7]};
                *(float4*)&h[(long)r * 256 + n0 + tx * 4]      = v0;
                *(float4*)&h[(long)r * 256 + n0 + 64 + tx * 4] = v1;
                if (tx == 0) {
                    as_[r * 4 + hd0] = ps0; ad_[r * 4 + hd0] = pd0;
                    as_[r * 4 + hd1] = ps1; ad_[r * 4 + hd1] = pd1;
                }
            }
        }
    }
}

// ---- global per-head max of alpha_src --------------------------------------
__global__ void gmax_init(unsigned* gmax) {
    if (threadIdx.x < 4) gmax[threadIdx.x] = 0u;
}
__global__ __launch_bounds__(256) void gmax_reduce(const float* __restrict__ as_,
                                                   unsigned* gmax) {
    float m0 = -1e30f, m1 = -1e30f, m2 = -1e30f, m3 = -1e30f;
    for (int n = blockIdx.x * 256 + threadIdx.x; n < NN; n += gridDim.x * 256) {
        float4 a = *(const float4*)&as_[n * 4];
        m0 = fmaxf(m0, a.x); m1 = fmaxf(m1, a.y);
        m2 = fmaxf(m2, a.z); m3 = fmaxf(m3, a.w);
    }
    #pragma unroll
    for (int off = 32; off; off >>= 1) {
        m0 = fmaxf(m0, __shfl_xor(m0, off, 64));
        m1 = fmaxf(m1, __shfl_xor(m1, off, 64));
        m2 = fmaxf(m2, __shfl_xor(m2, off, 64));
        m3 = fmaxf(m3, __shfl_xor(m3, off, 64));
    }
    __shared__ float sm[4][4];
    int lane = threadIdx.x & 63, w = threadIdx.x >> 6;
    if (lane == 0) { sm[w][0] = m0; sm[w][1] = m1; sm[w][2] = m2; sm[w][3] = m3; }
    __syncthreads();
    if (threadIdx.x == 0) {
        #pragma unroll
        for (int hd = 0; hd < 4; ++hd) {
            float mm = fmaxf(fmaxf(sm[0][hd], sm[1][hd]), fmaxf(sm[2][hd], sm[3][hd]));
            atomicMax(&gmax[hd], f2o(mm));
        }
    }
}

// ---- CSR-by-dst construction ----------------------------------------------
__global__ void init_counts(int* counts, int* esrc_pad) {
    int i = blockIdx.x * 256 + threadIdx.x;
    if (i < NN) counts[i] = 1;
    if (i == 0) esrc_pad[0] = 0;   // pad entry esrc[ET] -> valid node 0
}
__global__ void count_kernel(const int* __restrict__ dst, int* counts) {
    int e = blockIdx.x * 256 + threadIdx.x;
    if (e < NE) atomicAdd(&counts[dst[e]], 1);
}
__global__ __launch_bounds__(1024) void scan_kernel(const int* __restrict__ counts,
                                                    int* row_ptr, int* cursor) {
    __shared__ int sm[1024];
    const int i = threadIdx.x;
    const int CH = (NN + 1023) / 1024;
    int base = i * CH;
    int s = 0;
    for (int j = 0; j < CH; ++j) { int idx = base + j; if (idx < NN) s += counts[idx]; }
    sm[i] = s; __syncthreads();
    for (int off = 1; off < 1024; off <<= 1) {
        int v = (i >= off) ? sm[i - off] : 0;
        __syncthreads();
        sm[i] += v;
        __syncthreads();
    }
    int run = sm[i] - s;
    for (int j = 0; j < CH; ++j) {
        int idx = base + j;
        if (idx < NN) { row_ptr[idx] = run; cursor[idx] = run; run += counts[idx]; }
    }
    if (i == 1023) row_ptr[NN] = ET;
}
__global__ void scatter_kernel(const int* __restrict__ src, const int* __restrict__ dst,
                               int* cursor, int* esrc) {
    int e = blockIdx.x * 256 + threadIdx.x;
    if (e < NE) {
        int p = atomicAdd(&cursor[dst[e]], 1);
        esrc[p] = src[e];
    } else if (e < ET) {
        int n = e - NE;
        int p = atomicAdd(&cursor[n], 1);
        esrc[p] = n;
    }
}

// ---- single-pass segment softmax + aggregation (one wave per dst node) ----
// lane l: head = l>>4, channels 4l..4l+3  ->  h row gather is one dwordx4/edge
template<int FINAL>
__global__ __launch_bounds__(256) void agg_kernel(const float* __restrict__ h,
        const float* __restrict__ as_, const float* __restrict__ ad_,
        const unsigned* __restrict__ gmax,
        const int* __restrict__ row_ptr, const int* __restrict__ esrc,
        const float* __restrict__ bias, float* __restrict__ out,
        const int* __restrict__ batch, const float* __restrict__ fcW) {
    int n = blockIdx.x * 4 + (threadIdx.x >> 6);
    int lane = threadIdx.x & 63;
    if (n >= NN) return;
    const int head = lane >> 4;
    const int c4 = lane * 4;
    int s0 = row_ptr[n], s1 = row_ptr[n + 1];
    float adn = ad_[n * 4 + head];
    float g = o2f(gmax[head]) + adn; g = g > 0.f ? g : NEG * g;
    float lsum = 0.f;
    float4 acc = {0.f, 0.f, 0.f, 0.f};
    int s = esrc[s0];                       // >=1 edge (self-loop)
    float a = as_[s * 4 + head];
    for (int i = s0; i < s1; ++i) {
        int snext = esrc[i + 1];            // padded
        float anext = as_[snext * 4 + head];
        float4 hv = *(const float4*)&h[(long)s * 256 + c4];
        float t = a + adn; t = t > 0.f ? t : NEG * t;
        float w = __expf(t - g);
        lsum += w;
        acc.x = fmaf(w, hv.x, acc.x);
        acc.y = fmaf(w, hv.y, acc.y);
        acc.z = fmaf(w, hv.z, acc.z);
        acc.w = fmaf(w, hv.w, acc.w);
        s = snext; a = anext;
    }
    float rl = 1.f / lsum;
    float4 bv = *(const float4*)&bias[c4];
    float4 o = {fmaf(acc.x, rl, bv.x), fmaf(acc.y, rl, bv.y),
                fmaf(acc.z, rl, bv.z), fmaf(acc.w, rl, bv.w)};
    if (!FINAL) {
        *(float4*)&out[(long)n * 256 + c4] = o;
    } else {
        float4 fw = *(const float4*)&fcW[c4];
        float sd = o.x * fw.x + o.y * fw.y + o.z * fw.z + o.w * fw.w;
        #pragma unroll
        for (int off = 32; off; off >>= 1) sd += __shfl_xor(sd, off, 64);
        if (lane == 0) atomicAdd(&out[batch[n]], sd);
    }
}

// ---- output init ----------------------------------------------------------
__global__ void out_init(const float* __restrict__ fc_b, float* out) {
    int i = blockIdx.x * 256 + threadIdx.x;
    if (i < NG) out[i] = fc_b[0];
}

extern "C" void kernel_launch(void* const* d_in, const int* in_sizes, int n_in,
                              void* d_out, int out_size, void* d_ws, size_t ws_size,
                              hipStream_t stream) {
    const float* x      = (const float*)d_in[0];
    const int*   ei     = (const int*)d_in[1];
    const int*   batch  = (const int*)d_in[2];
    const float* W1     = (const float*)d_in[3];
    const float* as1    = (const float*)d_in[4];
    const float* ad1    = (const float*)d_in[5];
    const float* b1     = (const float*)d_in[6];
    const float* W2     = (const float*)d_in[7];
    const float* as2    = (const float*)d_in[8];
    const float* ad2    = (const float*)d_in[9];
    const float* b2     = (const float*)d_in[10];
    const float* W3     = (const float*)d_in[11];
    const float* as3    = (const float*)d_in[12];
    const float* ad3    = (const float*)d_in[13];
    const float* b3     = (const float*)d_in[14];
    const float* fcW    = (const float*)d_in[15];
    const float* fcb    = (const float*)d_in[16];
    const int* esrc_in = ei;
    const int* edst_in = ei + NE;

    char* ws = (char*)d_ws;
    size_t off = 0;
    float* bufA  = (float*)(ws + off); off += (size_t)NN * 256 * 4;
    float* bufB  = (float*)(ws + off); off += (size_t)NN * 256 * 4;
    float* aS    = (float*)(ws + off); off += (size_t)NN * 4 * 4;
    float* aD    = (float*)(ws + off); off += (size_t)NN * 4 * 4;
    int* counts  = (int*)(ws + off);   off += (size_t)NN * 4;
    int* cursor  = (int*)(ws + off);   off += (size_t)NN * 4;
    int* row_ptr = (int*)(ws + off);   off += (size_t)(NN + 1) * 4 + 12;
    unsigned* gmax = (unsigned*)(ws + off); off += 16;
    int* esrc    = (int*)(ws + off);   off += (size_t)(ET + 4) * 4;
    float* out   = (float*)d_out;

    // CSR by dst
    init_counts<<<(NN + 255) / 256, 256, 0, stream>>>(counts, esrc + ET);
    count_kernel<<<(NE + 255) / 256, 256, 0, stream>>>(edst_in, counts);
    scan_kernel<<<1, 1024, 0, stream>>>(counts, row_ptr, cursor);
    scatter_kernel<<<(ET + 255) / 256, 256, 0, stream>>>(esrc_in, edst_in, cursor, esrc);

    const int GEMM_GRID = ((NN + 127) / 128) * 2;   // 391 * 2
    const int NODE_GRID = (NN + 3) / 4;             // 12500

    // layer 1
    gmax_init<<<1, 64, 0, stream>>>(gmax);
    gemm_kernel<128><<<GEMM_GRID, 256, 0, stream>>>(x, W1, bufA, as1, ad1, aS, aD);
    gmax_reduce<<<128, 256, 0, stream>>>(aS, gmax);
    agg_kernel<0><<<NODE_GRID, 256, 0, stream>>>(bufA, aS, aD, gmax, row_ptr, esrc, b1, bufB, nullptr, nullptr);
    // layer 2
    gmax_init<<<1, 64, 0, stream>>>(gmax);
    gemm_kernel<256><<<GEMM_GRID, 256, 0, stream>>>(bufB, W2, bufA, as2, ad2, aS, aD);
    gmax_reduce<<<128, 256, 0, stream>>>(aS, gmax);
    agg_kernel<0><<<NODE_GRID, 256, 0, stream>>>(bufA, aS, aD, gmax, row_ptr, esrc, b2, bufB, nullptr, nullptr);
    // layer 3 (agg fused with pooling + FC)
    gmax_init<<<1, 64, 0, stream>>>(gmax);
    gemm_kernel<256><<<GEMM_GRID, 256, 0, stream>>>(bufB, W3, bufA, as3, ad3, aS, aD);
    gmax_reduce<<<128, 256, 0, stream>>>(aS, gmax);
    out_init<<<(NG + 255) / 256, 256, 0, stream>>>(fcb, out);
    agg_kernel<1><<<NODE_GRID, 256, 0, stream>>>(bufA, aS, aD, gmax, row_ptr, esrc, b3, out, batch, fcW);
}

// Round 4
// 926.391 us; speedup vs baseline: 1.3219x; 1.0313x over previous
//
#include <hip/hip_runtime.h>
#include <hip/hip_bf16.h>
#include <math.h>

#define NN 50000
#define NE 800000
#define ET (NE + NN)
#define NG 512
#define NEG 0.2f

__device__ inline unsigned f2o(float f) {
    unsigned b = __float_as_uint(f);
    return (b & 0x80000000u) ? ~b : (b | 0x80000000u);
}
__device__ inline float o2f(unsigned u) {
    return (u & 0x80000000u) ? __uint_as_float(u ^ 0x80000000u) : __uint_as_float(~u);
}

// ---- GEMM: h = x @ W  (M=NN, N=256), 128x128 tile, 8x8/thread, fused alpha
template<int K>
__global__ __launch_bounds__(256) void gemm_kernel(const float* __restrict__ x,
                                                   const float* __restrict__ W,
                                                   float* __restrict__ h,
                                                   const float* __restrict__ a_src,
                                                   const float* __restrict__ a_dst,
                                                   float* __restrict__ as_,
                                                   float* __restrict__ ad_) {
    __shared__ float As[16][132];
    __shared__ float Bs[16][132];
    const int t = threadIdx.x;
    const int tx = t & 15, ty = t >> 4;
    const int m0 = (blockIdx.x >> 1) * 128;
    const int n0 = (blockIdx.x & 1) * 128;
    float c[8][8] = {};
    const int lr = t >> 1;          // A row 0..127
    const int lk = (t & 1) * 8;     // A k-offset 0/8
    const int br = t >> 4;          // B row 0..15
    const int bc = (t & 15) * 8;    // B col 0..120

    for (int k0 = 0; k0 < K; k0 += 16) {
        int ar = m0 + lr; if (ar >= NN) ar = NN - 1;
        float4 a0 = *(const float4*)&x[(long)ar * K + k0 + lk];
        float4 a1 = *(const float4*)&x[(long)ar * K + k0 + lk + 4];
        float4 b0 = *(const float4*)&W[(long)(k0 + br) * 256 + n0 + bc];
        float4 b1 = *(const float4*)&W[(long)(k0 + br) * 256 + n0 + bc + 4];
        __syncthreads();
        As[lk + 0][lr] = a0.x; As[lk + 1][lr] = a0.y;
        As[lk + 2][lr] = a0.z; As[lk + 3][lr] = a0.w;
        As[lk + 4][lr] = a1.x; As[lk + 5][lr] = a1.y;
        As[lk + 6][lr] = a1.z; As[lk + 7][lr] = a1.w;
        *(float4*)&Bs[br][bc]     = b0;
        *(float4*)&Bs[br][bc + 4] = b1;
        __syncthreads();
        #pragma unroll
        for (int kk = 0; kk < 16; ++kk) {
            float4 A0 = *(const float4*)&As[kk][ty * 4];
            float4 A1 = *(const float4*)&As[kk][64 + ty * 4];
            float4 B0 = *(const float4*)&Bs[kk][tx * 4];
            float4 B1 = *(const float4*)&Bs[kk][64 + tx * 4];
            float av[8] = {A0.x, A0.y, A0.z, A0.w, A1.x, A1.y, A1.z, A1.w};
            float bv[8] = {B0.x, B0.y, B0.z, B0.w, B1.x, B1.y, B1.z, B1.w};
            #pragma unroll
            for (int i = 0; i < 8; ++i)
                #pragma unroll
                for (int j = 0; j < 8; ++j)
                    c[i][j] = fmaf(av[i], bv[j], c[i][j]);
        }
    }

    const int hd0 = n0 >> 6, hd1 = hd0 + 1;
    float4 s0v = *(const float4*)&a_src[hd0 * 64 + tx * 4];
    float4 s1v = *(const float4*)&a_src[hd1 * 64 + tx * 4];
    float4 d0v = *(const float4*)&a_dst[hd0 * 64 + tx * 4];
    float4 d1v = *(const float4*)&a_dst[hd1 * 64 + tx * 4];
    #pragma unroll
    for (int half = 0; half < 2; ++half) {
        #pragma unroll
        for (int i = 0; i < 4; ++i) {
            int ai = half * 4 + i;
            int r = m0 + half * 64 + ty * 4 + i;
            float ps0 = c[ai][0]*s0v.x + c[ai][1]*s0v.y + c[ai][2]*s0v.z + c[ai][3]*s0v.w;
            float pd0 = c[ai][0]*d0v.x + c[ai][1]*d0v.y + c[ai][2]*d0v.z + c[ai][3]*d0v.w;
            float ps1 = c[ai][4]*s1v.x + c[ai][5]*s1v.y + c[ai][6]*s1v.z + c[ai][7]*s1v.w;
            float pd1 = c[ai][4]*d1v.x + c[ai][5]*d1v.y + c[ai][6]*d1v.z + c[ai][7]*d1v.w;
            #pragma unroll
            for (int off = 1; off < 16; off <<= 1) {
                ps0 += __shfl_xor(ps0, off, 64);
                pd0 += __shfl_xor(pd0, off, 64);
                ps1 += __shfl_xor(ps1, off, 64);
                pd1 += __shfl_xor(pd1, off, 64);
            }
            if (r < NN) {
                float4 v0 = {c[ai][0], c[ai][1], c[ai][2], c[ai][3]};
                float4 v1 = {c[ai][4], c[ai][5], c[ai][6], c[ai][7]};
                *(float4*)&h[(long)r * 256 + n0 + tx * 4]      = v0;
                *(float4*)&h[(long)r * 256 + n0 + 64 + tx * 4] = v1;
                if (tx == 0) {
                    as_[r * 4 + hd0] = ps0; ad_[r * 4 + hd0] = pd0;
                    as_[r * 4 + hd1] = ps1; ad_[r * 4 + hd1] = pd1;
                }
            }
        }
    }
}

// ---- global per-head max of alpha_src --------------------------------------
__global__ void gmax_init(unsigned* gmax) {
    if (threadIdx.x < 4) gmax[threadIdx.x] = 0u;
}
__global__ __launch_bounds__(256) void gmax_reduce(const float* __restrict__ as_,
                                                   unsigned* gmax) {
    float m0 = -1e30f, m1 = -1e30f, m2 = -1e30f, m3 = -1e30f;
    for (int n = blockIdx.x * 256 + threadIdx.x; n < NN; n += gridDim.x * 256) {
        float4 a = *(const float4*)&as_[n * 4];
        m0 = fmaxf(m0, a.x); m1 = fmaxf(m1, a.y);
        m2 = fmaxf(m2, a.z); m3 = fmaxf(m3, a.w);
    }
    #pragma unroll
    for (int off = 32; off; off >>= 1) {
        m0 = fmaxf(m0, __shfl_xor(m0, off, 64));
        m1 = fmaxf(m1, __shfl_xor(m1, off, 64));
        m2 = fmaxf(m2, __shfl_xor(m2, off, 64));
        m3 = fmaxf(m3, __shfl_xor(m3, off, 64));
    }
    __shared__ float sm[4][4];
    int lane = threadIdx.x & 63, w = threadIdx.x >> 6;
    if (lane == 0) { sm[w][0] = m0; sm[w][1] = m1; sm[w][2] = m2; sm[w][3] = m3; }
    __syncthreads();
    if (threadIdx.x == 0) {
        #pragma unroll
        for (int hd = 0; hd < 4; ++hd) {
            float mm = fmaxf(fmaxf(sm[0][hd], sm[1][hd]), fmaxf(sm[2][hd], sm[3][hd]));
            atomicMax(&gmax[hd], f2o(mm));
        }
    }
}

// ---- CSR-by-dst construction ----------------------------------------------
__global__ void init_counts(int* counts, int* esrc_pad) {
    int i = blockIdx.x * 256 + threadIdx.x;
    if (i < NN) counts[i] = 1;
    if (i < 4) esrc_pad[i] = 0;   // pad entries esrc[ET..ET+3] -> valid node 0
}
__global__ void count_kernel(const int* __restrict__ dst, int* counts) {
    int e = blockIdx.x * 256 + threadIdx.x;
    if (e < NE) atomicAdd(&counts[dst[e]], 1);
}
__global__ __launch_bounds__(1024) void scan_kernel(const int* __restrict__ counts,
                                                    int* row_ptr, int* cursor) {
    __shared__ int sm[1024];
    const int i = threadIdx.x;
    const int CH = (NN + 1023) / 1024;
    int base = i * CH;
    int s = 0;
    for (int j = 0; j < CH; ++j) { int idx = base + j; if (idx < NN) s += counts[idx]; }
    sm[i] = s; __syncthreads();
    for (int off = 1; off < 1024; off <<= 1) {
        int v = (i >= off) ? sm[i - off] : 0;
        __syncthreads();
        sm[i] += v;
        __syncthreads();
    }
    int run = sm[i] - s;
    for (int j = 0; j < CH; ++j) {
        int idx = base + j;
        if (idx < NN) { row_ptr[idx] = run; cursor[idx] = run; run += counts[idx]; }
    }
    if (i == 1023) row_ptr[NN] = ET;
}
__global__ void scatter_kernel(const int* __restrict__ src, const int* __restrict__ dst,
                               int* cursor, int* esrc) {
    int e = blockIdx.x * 256 + threadIdx.x;
    if (e < NE) {
        int p = atomicAdd(&cursor[dst[e]], 1);
        esrc[p] = src[e];
    } else if (e < ET) {
        int n = e - NE;
        int p = atomicAdd(&cursor[n], 1);
        esrc[p] = n;
    }
}

// ---- single-pass segment softmax + aggregation (one wave per dst node) ----
// lane l: head = l>>4, channels 4l..4l+3; edge loop unrolled x4 for MLP
template<int FINAL>
__global__ __launch_bounds__(256) void agg_kernel(const float* __restrict__ h,
        const float* __restrict__ as_, const float* __restrict__ ad_,
        const unsigned* __restrict__ gmax,
        const int* __restrict__ row_ptr, const int* __restrict__ esrc,
        const float* __restrict__ bias, float* __restrict__ out,
        const int* __restrict__ batch, const float* __restrict__ fcW) {
    int n = blockIdx.x * 4 + (threadIdx.x >> 6);
    int lane = threadIdx.x & 63;
    if (n >= NN) return;
    const int head = lane >> 4;
    const int c4 = lane * 4;
    int s0 = row_ptr[n], s1 = row_ptr[n + 1];
    float adn = ad_[n * 4 + head];
    float g = o2f(gmax[head]) + adn; g = g > 0.f ? g : NEG * g;
    float lsum = 0.f;
    float4 acc = {0.f, 0.f, 0.f, 0.f};

    int i = s0;
    for (; i + 4 <= s1; i += 4) {
        int sa = esrc[i], sb = esrc[i + 1], sc = esrc[i + 2], sd = esrc[i + 3];
        float aa = as_[sa * 4 + head];
        float ab = as_[sb * 4 + head];
        float ac = as_[sc * 4 + head];
        float ae = as_[sd * 4 + head];
        float4 ha = *(const float4*)&h[(long)sa * 256 + c4];
        float4 hb = *(const float4*)&h[(long)sb * 256 + c4];
        float4 hc = *(const float4*)&h[(long)sc * 256 + c4];
        float4 hd = *(const float4*)&h[(long)sd * 256 + c4];
        float t, w;
        t = aa + adn; t = t > 0.f ? t : NEG * t; w = __expf(t - g); lsum += w;
        acc.x = fmaf(w, ha.x, acc.x); acc.y = fmaf(w, ha.y, acc.y);
        acc.z = fmaf(w, ha.z, acc.z); acc.w = fmaf(w, ha.w, acc.w);
        t = ab + adn; t = t > 0.f ? t : NEG * t; w = __expf(t - g); lsum += w;
        acc.x = fmaf(w, hb.x, acc.x); acc.y = fmaf(w, hb.y, acc.y);
        acc.z = fmaf(w, hb.z, acc.z); acc.w = fmaf(w, hb.w, acc.w);
        t = ac + adn; t = t > 0.f ? t : NEG * t; w = __expf(t - g); lsum += w;
        acc.x = fmaf(w, hc.x, acc.x); acc.y = fmaf(w, hc.y, acc.y);
        acc.z = fmaf(w, hc.z, acc.z); acc.w = fmaf(w, hc.w, acc.w);
        t = ae + adn; t = t > 0.f ? t : NEG * t; w = __expf(t - g); lsum += w;
        acc.x = fmaf(w, hd.x, acc.x); acc.y = fmaf(w, hd.y, acc.y);
        acc.z = fmaf(w, hd.z, acc.z); acc.w = fmaf(w, hd.w, acc.w);
    }
    for (; i < s1; ++i) {
        int s = esrc[i];
        float a = as_[s * 4 + head];
        float4 hv = *(const float4*)&h[(long)s * 256 + c4];
        float t = a + adn; t = t > 0.f ? t : NEG * t;
        float w = __expf(t - g); lsum += w;
        acc.x = fmaf(w, hv.x, acc.x); acc.y = fmaf(w, hv.y, acc.y);
        acc.z = fmaf(w, hv.z, acc.z); acc.w = fmaf(w, hv.w, acc.w);
    }

    float rl = 1.f / lsum;
    float4 bv = *(const float4*)&bias[c4];
    float4 o = {fmaf(acc.x, rl, bv.x), fmaf(acc.y, rl, bv.y),
                fmaf(acc.z, rl, bv.z), fmaf(acc.w, rl, bv.w)};
    if (!FINAL) {
        *(float4*)&out[(long)n * 256 + c4] = o;
    } else {
        float4 fw = *(const float4*)&fcW[c4];
        float sd = o.x * fw.x + o.y * fw.y + o.z * fw.z + o.w * fw.w;
        #pragma unroll
        for (int off = 32; off; off >>= 1) sd += __shfl_xor(sd, off, 64);
        if (lane == 0) atomicAdd(&out[batch[n]], sd);
    }
}

// ---- output init ----------------------------------------------------------
__global__ void out_init(const float* __restrict__ fc_b, float* out) {
    int i = blockIdx.x * 256 + threadIdx.x;
    if (i < NG) out[i] = fc_b[0];
}

extern "C" void kernel_launch(void* const* d_in, const int* in_sizes, int n_in,
                              void* d_out, int out_size, void* d_ws, size_t ws_size,
                              hipStream_t stream) {
    const float* x      = (const float*)d_in[0];
    const int*   ei     = (const int*)d_in[1];
    const int*   batch  = (const int*)d_in[2];
    const float* W1     = (const float*)d_in[3];
    const float* as1    = (const float*)d_in[4];
    const float* ad1    = (const float*)d_in[5];
    const float* b1     = (const float*)d_in[6];
    const float* W2     = (const float*)d_in[7];
    const float* as2    = (const float*)d_in[8];
    const float* ad2    = (const float*)d_in[9];
    const float* b2     = (const float*)d_in[10];
    const float* W3     = (const float*)d_in[11];
    const float* as3    = (const float*)d_in[12];
    const float* ad3    = (const float*)d_in[13];
    const float* b3     = (const float*)d_in[14];
    const float* fcW    = (const float*)d_in[15];
    const float* fcb    = (const float*)d_in[16];
    const int* esrc_in = ei;
    const int* edst_in = ei + NE;

    char* ws = (char*)d_ws;
    size_t off = 0;
    float* bufA  = (float*)(ws + off); off += (size_t)NN * 256 * 4;
    float* bufB  = (float*)(ws + off); off += (size_t)NN * 256 * 4;
    float* aS    = (float*)(ws + off); off += (size_t)NN * 4 * 4;
    float* aD    = (float*)(ws + off); off += (size_t)NN * 4 * 4;
    int* counts  = (int*)(ws + off);   off += (size_t)NN * 4;
    int* cursor  = (int*)(ws + off);   off += (size_t)NN * 4;
    int* row_ptr = (int*)(ws + off);   off += (size_t)(NN + 1) * 4 + 12;
    unsigned* gmax = (unsigned*)(ws + off); off += 16;
    int* esrc    = (int*)(ws + off);   off += (size_t)(ET + 4) * 4;
    float* out   = (float*)d_out;

    // CSR by dst
    init_counts<<<(NN + 255) / 256, 256, 0, stream>>>(counts, esrc + ET);
    count_kernel<<<(NE + 255) / 256, 256, 0, stream>>>(edst_in, counts);
    scan_kernel<<<1, 1024, 0, stream>>>(counts, row_ptr, cursor);
    scatter_kernel<<<(ET + 255) / 256, 256, 0, stream>>>(esrc_in, edst_in, cursor, esrc);

    const int GEMM_GRID = ((NN + 127) / 128) * 2;   // 391 * 2
    const int NODE_GRID = (NN + 3) / 4;             // 12500

    // layer 1
    gmax_init<<<1, 64, 0, stream>>>(gmax);
    gemm_kernel<128><<<GEMM_GRID, 256, 0, stream>>>(x, W1, bufA, as1, ad1, aS, aD);
    gmax_reduce<<<128, 256, 0, stream>>>(aS, gmax);
    agg_kernel<0><<<NODE_GRID, 256, 0, stream>>>(bufA, aS, aD, gmax, row_ptr, esrc, b1, bufB, nullptr, nullptr);
    // layer 2
    gmax_init<<<1, 64, 0, stream>>>(gmax);
    gemm_kernel<256><<<GEMM_GRID, 256, 0, stream>>>(bufB, W2, bufA, as2, ad2, aS, aD);
    gmax_reduce<<<128, 256, 0, stream>>>(aS, gmax);
    agg_kernel<0><<<NODE_GRID, 256, 0, stream>>>(bufA, aS, aD, gmax, row_ptr, esrc, b2, bufB, nullptr, nullptr);
    // layer 3 (agg fused with pooling + FC)
    gmax_init<<<1, 64, 0, stream>>>(gmax);
    gemm_kernel<256><<<GEMM_GRID, 256, 0, stream>>>(bufB, W3, bufA, as3, ad3, aS, aD);
    gmax_reduce<<<128, 256, 0, stream>>>(aS, gmax);
    out_init<<<(NG + 255) / 256, 256, 0, stream>>>(fcb, out);
    agg_kernel<1><<<NODE_GRID, 256, 0, stream>>>(bufA, aS, aD, gmax, row_ptr, esrc, b3, out, batch, fcW);
}

// Round 5
// 786.542 us; speedup vs baseline: 1.5570x; 1.1778x over previous
//
#include <hip/hip_runtime.h>
#include <hip/hip_bf16.h>
#include <math.h>

#define NN 50000
#define NE 800000
#define ET (NE + NN)
#define NG 512
#define NEG 0.2f

__device__ inline unsigned f2o(float f) {
    unsigned b = __float_as_uint(f);
    return (b & 0x80000000u) ? ~b : (b | 0x80000000u);
}
__device__ inline float o2f(unsigned u) {
    return (u & 0x80000000u) ? __uint_as_float(u ^ 0x80000000u) : __uint_as_float(~u);
}
__device__ inline unsigned short f2b(float f) {   // fp32 -> bf16 RNE
    unsigned u = __float_as_uint(f);
    u += 0x7fffu + ((u >> 16) & 1u);
    return (unsigned short)(u >> 16);
}
__device__ inline float b2f(unsigned short b) {
    return __uint_as_float(((unsigned)b) << 16);
}

// ---- GEMM: h = x @ W (M=NN, N=256), 128x128 tile, 8x8/thread --------------
// writes h in bf16; fused alpha_src/alpha_dst epilogue from fp32 accumulators
template<int K>
__global__ __launch_bounds__(256) void gemm_kernel(const float* __restrict__ x,
                                                   const float* __restrict__ W,
                                                   unsigned short* __restrict__ h,
                                                   const float* __restrict__ a_src,
                                                   const float* __restrict__ a_dst,
                                                   float* __restrict__ as_,
                                                   float* __restrict__ ad_) {
    __shared__ float As[16][132];
    __shared__ float Bs[16][132];
    const int t = threadIdx.x;
    const int tx = t & 15, ty = t >> 4;
    const int m0 = (blockIdx.x >> 1) * 128;
    const int n0 = (blockIdx.x & 1) * 128;
    float c[8][8] = {};
    const int lr = t >> 1;
    const int lk = (t & 1) * 8;
    const int br = t >> 4;
    const int bc = (t & 15) * 8;

    for (int k0 = 0; k0 < K; k0 += 16) {
        int ar = m0 + lr; if (ar >= NN) ar = NN - 1;
        float4 a0 = *(const float4*)&x[(long)ar * K + k0 + lk];
        float4 a1 = *(const float4*)&x[(long)ar * K + k0 + lk + 4];
        float4 b0 = *(const float4*)&W[(long)(k0 + br) * 256 + n0 + bc];
        float4 b1 = *(const float4*)&W[(long)(k0 + br) * 256 + n0 + bc + 4];
        __syncthreads();
        As[lk + 0][lr] = a0.x; As[lk + 1][lr] = a0.y;
        As[lk + 2][lr] = a0.z; As[lk + 3][lr] = a0.w;
        As[lk + 4][lr] = a1.x; As[lk + 5][lr] = a1.y;
        As[lk + 6][lr] = a1.z; As[lk + 7][lr] = a1.w;
        *(float4*)&Bs[br][bc]     = b0;
        *(float4*)&Bs[br][bc + 4] = b1;
        __syncthreads();
        #pragma unroll
        for (int kk = 0; kk < 16; ++kk) {
            float4 A0 = *(const float4*)&As[kk][ty * 4];
            float4 A1 = *(const float4*)&As[kk][64 + ty * 4];
            float4 B0 = *(const float4*)&Bs[kk][tx * 4];
            float4 B1 = *(const float4*)&Bs[kk][64 + tx * 4];
            float av[8] = {A0.x, A0.y, A0.z, A0.w, A1.x, A1.y, A1.z, A1.w};
            float bv[8] = {B0.x, B0.y, B0.z, B0.w, B1.x, B1.y, B1.z, B1.w};
            #pragma unroll
            for (int i = 0; i < 8; ++i)
                #pragma unroll
                for (int j = 0; j < 8; ++j)
                    c[i][j] = fmaf(av[i], bv[j], c[i][j]);
        }
    }

    const int hd0 = n0 >> 6, hd1 = hd0 + 1;
    float4 s0v = *(const float4*)&a_src[hd0 * 64 + tx * 4];
    float4 s1v = *(const float4*)&a_src[hd1 * 64 + tx * 4];
    float4 d0v = *(const float4*)&a_dst[hd0 * 64 + tx * 4];
    float4 d1v = *(const float4*)&a_dst[hd1 * 64 + tx * 4];
    #pragma unroll
    for (int half = 0; half < 2; ++half) {
        #pragma unroll
        for (int i = 0; i < 4; ++i) {
            int ai = half * 4 + i;
            int r = m0 + half * 64 + ty * 4 + i;
            float ps0 = c[ai][0]*s0v.x + c[ai][1]*s0v.y + c[ai][2]*s0v.z + c[ai][3]*s0v.w;
            float pd0 = c[ai][0]*d0v.x + c[ai][1]*d0v.y + c[ai][2]*d0v.z + c[ai][3]*d0v.w;
            float ps1 = c[ai][4]*s1v.x + c[ai][5]*s1v.y + c[ai][6]*s1v.z + c[ai][7]*s1v.w;
            float pd1 = c[ai][4]*d1v.x + c[ai][5]*d1v.y + c[ai][6]*d1v.z + c[ai][7]*d1v.w;
            #pragma unroll
            for (int off = 1; off < 16; off <<= 1) {
                ps0 += __shfl_xor(ps0, off, 64);
                pd0 += __shfl_xor(pd0, off, 64);
                ps1 += __shfl_xor(ps1, off, 64);
                pd1 += __shfl_xor(pd1, off, 64);
            }
            if (r < NN) {
                ushort4 v0 = {f2b(c[ai][0]), f2b(c[ai][1]), f2b(c[ai][2]), f2b(c[ai][3])};
                ushort4 v1 = {f2b(c[ai][4]), f2b(c[ai][5]), f2b(c[ai][6]), f2b(c[ai][7])};
                *(ushort4*)&h[(long)r * 256 + n0 + tx * 4]      = v0;
                *(ushort4*)&h[(long)r * 256 + n0 + 64 + tx * 4] = v1;
                if (tx == 0) {
                    as_[r * 4 + hd0] = ps0; ad_[r * 4 + hd0] = pd0;
                    as_[r * 4 + hd1] = ps1; ad_[r * 4 + hd1] = pd1;
                }
            }
        }
    }
}

// ---- global per-head max of alpha_src --------------------------------------
__global__ void gmax_init(unsigned* gmax) {
    if (threadIdx.x < 4) gmax[threadIdx.x] = 0u;
}
__global__ __launch_bounds__(256) void gmax_reduce(const float* __restrict__ as_,
                                                   unsigned* gmax) {
    float m0 = -1e30f, m1 = -1e30f, m2 = -1e30f, m3 = -1e30f;
    for (int n = blockIdx.x * 256 + threadIdx.x; n < NN; n += gridDim.x * 256) {
        float4 a = *(const float4*)&as_[n * 4];
        m0 = fmaxf(m0, a.x); m1 = fmaxf(m1, a.y);
        m2 = fmaxf(m2, a.z); m3 = fmaxf(m3, a.w);
    }
    #pragma unroll
    for (int off = 32; off; off >>= 1) {
        m0 = fmaxf(m0, __shfl_xor(m0, off, 64));
        m1 = fmaxf(m1, __shfl_xor(m1, off, 64));
        m2 = fmaxf(m2, __shfl_xor(m2, off, 64));
        m3 = fmaxf(m3, __shfl_xor(m3, off, 64));
    }
    __shared__ float sm[4][4];
    int lane = threadIdx.x & 63, w = threadIdx.x >> 6;
    if (lane == 0) { sm[w][0] = m0; sm[w][1] = m1; sm[w][2] = m2; sm[w][3] = m3; }
    __syncthreads();
    if (threadIdx.x == 0) {
        #pragma unroll
        for (int hd = 0; hd < 4; ++hd) {
            float mm = fmaxf(fmaxf(sm[0][hd], sm[1][hd]), fmaxf(sm[2][hd], sm[3][hd]));
            atomicMax(&gmax[hd], f2o(mm));
        }
    }
}

// ---- CSR-by-dst construction ----------------------------------------------
__global__ void init_counts(int* counts, int* esrc_pad) {
    int i = blockIdx.x * 256 + threadIdx.x;
    if (i < NN) counts[i] = 1;
    if (i < 8) esrc_pad[i] = 0;   // pad esrc[ET..ET+7] -> valid node 0
}
__global__ void count_kernel(const int* __restrict__ dst, int* counts) {
    int e = blockIdx.x * 256 + threadIdx.x;
    if (e < NE) atomicAdd(&counts[dst[e]], 1);
}
__global__ __launch_bounds__(1024) void scan_kernel(const int* __restrict__ counts,
                                                    int* row_ptr, int* cursor) {
    __shared__ int sm[1024];
    const int i = threadIdx.x;
    const int CH = (NN + 1023) / 1024;
    int base = i * CH;
    int s = 0;
    for (int j = 0; j < CH; ++j) { int idx = base + j; if (idx < NN) s += counts[idx]; }
    sm[i] = s; __syncthreads();
    for (int off = 1; off < 1024; off <<= 1) {
        int v = (i >= off) ? sm[i - off] : 0;
        __syncthreads();
        sm[i] += v;
        __syncthreads();
    }
    int run = sm[i] - s;
    for (int j = 0; j < CH; ++j) {
        int idx = base + j;
        if (idx < NN) { row_ptr[idx] = run; cursor[idx] = run; run += counts[idx]; }
    }
    if (i == 1023) row_ptr[NN] = ET;
}
__global__ void scatter_kernel(const int* __restrict__ src, const int* __restrict__ dst,
                               int* cursor, int* esrc) {
    int e = blockIdx.x * 256 + threadIdx.x;
    if (e < NE) {
        int p = atomicAdd(&cursor[dst[e]], 1);
        esrc[p] = src[e];
    } else if (e < ET) {
        int n = e - NE;
        int p = atomicAdd(&cursor[n], 1);
        esrc[p] = n;
    }
}

// ---- segment softmax + aggregation: one wave/node, bf16 payload,
// 4-edge groups with explicit next-group index/alpha prefetch pipeline ------
template<int FINAL>
__global__ __launch_bounds__(256) void agg_kernel(const unsigned short* __restrict__ h,
        const float* __restrict__ as_, const float* __restrict__ ad_,
        const unsigned* __restrict__ gmax,
        const int* __restrict__ row_ptr, const int* __restrict__ esrc,
        const float* __restrict__ bias, float* __restrict__ out,
        const int* __restrict__ batch, const float* __restrict__ fcW) {
    int n = blockIdx.x * 4 + (threadIdx.x >> 6);
    int lane = threadIdx.x & 63;
    if (n >= NN) return;
    const int head = lane >> 4;
    const int c4 = lane * 4;
    int s0 = row_ptr[n], s1 = row_ptr[n + 1];
    float adn = ad_[n * 4 + head];
    float g = o2f(gmax[head]) + adn; g = g > 0.f ? g : NEG * g;
    float lsum = 0.f;
    float4 acc = {0.f, 0.f, 0.f, 0.f};

    int i = s0;
    // prologue: group-0 indices + alphas (esrc padded by 8, always in-bounds)
    int i0 = esrc[i], i1 = esrc[i + 1], i2 = esrc[i + 2], i3 = esrc[i + 3];
    float a0 = as_[i0 * 4 + head], a1 = as_[i1 * 4 + head];
    float a2 = as_[i2 * 4 + head], a3 = as_[i3 * 4 + head];

    while (i + 4 <= s1) {
        // issue this group's h-gathers (bf16x4 = 8B/lane, 512B/wave each)
        ushort4 h0 = *(const ushort4*)&h[(long)i0 * 256 + c4];
        ushort4 h1 = *(const ushort4*)&h[(long)i1 * 256 + c4];
        ushort4 h2 = *(const ushort4*)&h[(long)i2 * 256 + c4];
        ushort4 h3 = *(const ushort4*)&h[(long)i3 * 256 + c4];
        // prefetch next group's indices + alphas while gathers are in flight
        int j = i + 4;
        int p0 = esrc[j], p1 = esrc[j + 1], p2 = esrc[j + 2], p3 = esrc[j + 3];
        float b0 = as_[p0 * 4 + head], b1 = as_[p1 * 4 + head];
        float b2 = as_[p2 * 4 + head], b3 = as_[p3 * 4 + head];
        // compute current group
        float t, w;
        t = a0 + adn; t = t > 0.f ? t : NEG * t; w = __expf(t - g); lsum += w;
        acc.x = fmaf(w, b2f(h0.x), acc.x); acc.y = fmaf(w, b2f(h0.y), acc.y);
        acc.z = fmaf(w, b2f(h0.z), acc.z); acc.w = fmaf(w, b2f(h0.w), acc.w);
        t = a1 + adn; t = t > 0.f ? t : NEG * t; w = __expf(t - g); lsum += w;
        acc.x = fmaf(w, b2f(h1.x), acc.x); acc.y = fmaf(w, b2f(h1.y), acc.y);
        acc.z = fmaf(w, b2f(h1.z), acc.z); acc.w = fmaf(w, b2f(h1.w), acc.w);
        t = a2 + adn; t = t > 0.f ? t : NEG * t; w = __expf(t - g); lsum += w;
        acc.x = fmaf(w, b2f(h2.x), acc.x); acc.y = fmaf(w, b2f(h2.y), acc.y);
        acc.z = fmaf(w, b2f(h2.z), acc.z); acc.w = fmaf(w, b2f(h2.w), acc.w);
        t = a3 + adn; t = t > 0.f ? t : NEG * t; w = __expf(t - g); lsum += w;
        acc.x = fmaf(w, b2f(h3.x), acc.x); acc.y = fmaf(w, b2f(h3.y), acc.y);
        acc.z = fmaf(w, b2f(h3.z), acc.z); acc.w = fmaf(w, b2f(h3.w), acc.w);
        i0 = p0; i1 = p1; i2 = p2; i3 = p3;
        a0 = b0; a1 = b1; a2 = b2; a3 = b3;
        i = j;
    }
    for (; i < s1; ++i) {
        int s = esrc[i];
        float a = as_[s * 4 + head];
        ushort4 hv = *(const ushort4*)&h[(long)s * 256 + c4];
        float t = a + adn; t = t > 0.f ? t : NEG * t;
        float w = __expf(t - g); lsum += w;
        acc.x = fmaf(w, b2f(hv.x), acc.x); acc.y = fmaf(w, b2f(hv.y), acc.y);
        acc.z = fmaf(w, b2f(hv.z), acc.z); acc.w = fmaf(w, b2f(hv.w), acc.w);
    }

    float rl = 1.f / lsum;
    float4 bv = *(const float4*)&bias[c4];
    float4 o = {fmaf(acc.x, rl, bv.x), fmaf(acc.y, rl, bv.y),
                fmaf(acc.z, rl, bv.z), fmaf(acc.w, rl, bv.w)};
    if (!FINAL) {
        *(float4*)&out[(long)n * 256 + c4] = o;
    } else {
        float4 fw = *(const float4*)&fcW[c4];
        float sd = o.x * fw.x + o.y * fw.y + o.z * fw.z + o.w * fw.w;
        #pragma unroll
        for (int off = 32; off; off >>= 1) sd += __shfl_xor(sd, off, 64);
        if (lane == 0) atomicAdd(&out[batch[n]], sd);
    }
}

// ---- output init ----------------------------------------------------------
__global__ void out_init(const float* __restrict__ fc_b, float* out) {
    int i = blockIdx.x * 256 + threadIdx.x;
    if (i < NG) out[i] = fc_b[0];
}

extern "C" void kernel_launch(void* const* d_in, const int* in_sizes, int n_in,
                              void* d_out, int out_size, void* d_ws, size_t ws_size,
                              hipStream_t stream) {
    const float* x      = (const float*)d_in[0];
    const int*   ei     = (const int*)d_in[1];
    const int*   batch  = (const int*)d_in[2];
    const float* W1     = (const float*)d_in[3];
    const float* as1    = (const float*)d_in[4];
    const float* ad1    = (const float*)d_in[5];
    const float* b1     = (const float*)d_in[6];
    const float* W2     = (const float*)d_in[7];
    const float* as2    = (const float*)d_in[8];
    const float* ad2    = (const float*)d_in[9];
    const float* b2     = (const float*)d_in[10];
    const float* W3     = (const float*)d_in[11];
    const float* as3    = (const float*)d_in[12];
    const float* ad3    = (const float*)d_in[13];
    const float* b3     = (const float*)d_in[14];
    const float* fcW    = (const float*)d_in[15];
    const float* fcb    = (const float*)d_in[16];
    const int* esrc_in = ei;
    const int* edst_in = ei + NE;

    char* ws = (char*)d_ws;
    size_t off = 0;
    unsigned short* hB = (unsigned short*)(ws + off); off += (size_t)NN * 256 * 2;
    float* aggF  = (float*)(ws + off); off += (size_t)NN * 256 * 4;
    float* aS    = (float*)(ws + off); off += (size_t)NN * 4 * 4;
    float* aD    = (float*)(ws + off); off += (size_t)NN * 4 * 4;
    int* counts  = (int*)(ws + off);   off += (size_t)NN * 4;
    int* cursor  = (int*)(ws + off);   off += (size_t)NN * 4;
    int* row_ptr = (int*)(ws + off);   off += (size_t)(NN + 1) * 4 + 12;
    unsigned* gmax = (unsigned*)(ws + off); off += 16;
    int* esrc    = (int*)(ws + off);   off += (size_t)(ET + 8) * 4;
    float* out   = (float*)d_out;

    // CSR by dst
    init_counts<<<(NN + 255) / 256, 256, 0, stream>>>(counts, esrc + ET);
    count_kernel<<<(NE + 255) / 256, 256, 0, stream>>>(edst_in, counts);
    scan_kernel<<<1, 1024, 0, stream>>>(counts, row_ptr, cursor);
    scatter_kernel<<<(ET + 255) / 256, 256, 0, stream>>>(esrc_in, edst_in, cursor, esrc);

    const int GEMM_GRID = ((NN + 127) / 128) * 2;
    const int NODE_GRID = (NN + 3) / 4;

    // layer 1
    gmax_init<<<1, 64, 0, stream>>>(gmax);
    gemm_kernel<128><<<GEMM_GRID, 256, 0, stream>>>(x, W1, hB, as1, ad1, aS, aD);
    gmax_reduce<<<128, 256, 0, stream>>>(aS, gmax);
    agg_kernel<0><<<NODE_GRID, 256, 0, stream>>>(hB, aS, aD, gmax, row_ptr, esrc, b1, aggF, nullptr, nullptr);
    // layer 2
    gmax_init<<<1, 64, 0, stream>>>(gmax);
    gemm_kernel<256><<<GEMM_GRID, 256, 0, stream>>>(aggF, W2, hB, as2, ad2, aS, aD);
    gmax_reduce<<<128, 256, 0, stream>>>(aS, gmax);
    agg_kernel<0><<<NODE_GRID, 256, 0, stream>>>(hB, aS, aD, gmax, row_ptr, esrc, b2, aggF, nullptr, nullptr);
    // layer 3 (agg fused with pooling + FC)
    gmax_init<<<1, 64, 0, stream>>>(gmax);
    gemm_kernel<256><<<GEMM_GRID, 256, 0, stream>>>(aggF, W3, hB, as3, ad3, aS, aD);
    gmax_reduce<<<128, 256, 0, stream>>>(aS, gmax);
    out_init<<<(NG + 255) / 256, 256, 0, stream>>>(fcb, out);
    agg_kernel<1><<<NODE_GRID, 256, 0, stream>>>(hB, aS, aD, gmax, row_ptr, esrc, b3, out, batch, fcW);
}